// Round 12
// baseline (216.876 us; speedup 1.0000x reference)
//
#include <hip/hip_runtime.h>
#include <cstdint>
#include <cstddef>

#define LQ   2048
#define BQ   4
#define EQ   1024
#define HQ   8
#define D1Q  2048
#define HDQ  256
#define NBQ  (LQ*BQ)   // 8192 rows in (n,b) layout

typedef __bf16 bf16_t;
typedef __bf16 bf16x8 __attribute__((ext_vector_type(8)));
typedef __bf16 bf16x4 __attribute__((ext_vector_type(4)));
typedef float  f32x4  __attribute__((ext_vector_type(4)));

#define GAS1(p) ((const __attribute__((address_space(1))) void*)(p))
#define LAS3(p) ((__attribute__((address_space(3))) void*)(p))

// ---------------------------------------------------------------- utilities

__global__ __launch_bounds__(256) void convert_kernel(
    const float* __restrict__ Wu, const float* __restrict__ Wv,
    const float* __restrict__ Wo,
    bf16_t* __restrict__ Wub, bf16_t* __restrict__ Wvb,
    bf16_t* __restrict__ Wob)
{
    const size_t i = (size_t)blockIdx.x * 256 + threadIdx.x;
    if (i < (size_t)D1Q * EQ) {
        Wub[i] = (bf16_t)Wu[i];
        Wvb[i] = (bf16_t)Wv[i];
        Wob[i] = (bf16_t)Wo[i];
    }
}

// Toeplitz A-tiles: 128x32 (BK=32), diag offset (q-3)*32, 64 tiles x 8 heads.
__global__ __launch_bounds__(256) void build_toep_tiles(
    const float* __restrict__ zero, const float* __restrict__ pos,
    bf16_t* __restrict__ Atiles)
{
    const int q = blockIdx.x;        // 0..63
    const int h = blockIdx.y;        // 0..7
    const int doff = (q - 3) * 32;
    const int tid = threadIdx.x;
    bf16_t* dst = Atiles + ((size_t)h * 64 + q) * (128 * 32);
    const int e0 = tid * 16;
    const int r = e0 >> 5;
    const int cbase = e0 & 31;
    bf16_t vals[16];
    #pragma unroll
    for (int j = 0; j < 16; ++j) {
        const int d = doff + r - (cbase + j);
        float v = 0.f;
        if (d == 0) v = zero[h];
        else if (d > 0) v = pos[(size_t)h * (LQ - 1) + d - 1];
        vals[j] = (bf16_t)v;
    }
    *(bf16x8*)(dst + e0)     = *(bf16x8*)(vals);
    *(bf16x8*)(dst + e0 + 8) = *(bf16x8*)(vals + 8);
}

__global__ __launch_bounds__(256) void rmsnorm_kernel(
    const float* __restrict__ x, bf16_t* __restrict__ xn)
{
    const int row = blockIdx.x;           // 0..8191
    const int tid = threadIdx.x;
    const float4 v = ((const float4*)(x + (size_t)row * EQ))[tid];
    float ss = v.x*v.x + v.y*v.y + v.z*v.z + v.w*v.w;
    #pragma unroll
    for (int m = 32; m >= 1; m >>= 1) ss += __shfl_xor(ss, m, 64);
    __shared__ float red[4];
    const int wid = tid >> 6, lane = tid & 63;
    if (lane == 0) red[wid] = ss;
    __syncthreads();
    const float tot = red[0] + red[1] + red[2] + red[3];
    const float inv = 1.f / (sqrtf(tot * (1.f / EQ)) + 1e-8f);
    bf16x4 o;
    o[0] = (bf16_t)(v.x * inv); o[1] = (bf16_t)(v.y * inv);
    o[2] = (bf16_t)(v.z * inv); o[3] = (bf16_t)(v.w * inv);
    *(bf16x4*)(xn + (size_t)row * EQ + tid * 4) = o;
}

// ================================================================ uniform K-loop
// All hot GEMMs: 256 threads = 4 waves (2M x 2N), BM=BN=128, BK=32, wave tile
// 64x64, acc[4][4].  Triple-buffered LDS 3 x 16K = 48 KB -> 3 blocks/CU.
// Prefetch distance 2; boundary wait vmcnt(4) (t+2's 4 loads in flight, never 0
// until tail); ONE barrier per tile; setprio around MFMA.
// Swizzle (verified conflict-free): 16B slot ^= (row>>1)&3, both sides.

// ---------------------------------------------------------------- merged U+V GEMM
// B = [Wu; Wv] (4096 rows).  bx<16 -> U (silu, row-major nb x d1);
// bx>=16 -> V (silu, (h,b,hd,t) via single-pass LDS transpose, 64-B t-runs).
__global__ __launch_bounds__(256, 3) void gemm_uv(
    const bf16_t* __restrict__ A, const bf16_t* __restrict__ Bm,
    const float* __restrict__ bbu, const float* __restrict__ bbv,
    bf16_t* __restrict__ Ub, bf16_t* __restrict__ Vt)
{
    constexpr int K = EQ;            // 1024
    constexpr int BUF = 16384;       // A 8K + B 8K
    __shared__ alignas(16) char smem[3 * BUF];   // 48 KB

    // XCD-chunked bijective swizzle (nwg = 2048)
    const int nwg   = gridDim.x * gridDim.y;
    const int bid0  = blockIdx.y * gridDim.x + blockIdx.x;
    const int chunkw = nwg >> 3;
    const int sb    = (bid0 & 7) * chunkw + (bid0 >> 3);
    const int bx    = sb % gridDim.x;
    const int by    = sb / gridDim.x;

    const int tid  = threadIdx.x;
    const int wid  = tid >> 6;
    const int lane = tid & 63;
    const int frow = lane & 15;
    const int c    = lane >> 4;
    const int m0 = by * 128;
    const int n0 = bx * 128;
    const int wm = wid >> 1, wn = wid & 1;
    const int wrm = wm * 64, wrn = wn * 64;

    const int g = (frow >> 1) & 3;
    const int offA0 = (wrm + frow) * 64 + ((c ^ g) << 4);
    const int offB0 = 8192 + (wrn + frow) * 64 + ((c ^ g) << 4);

    const int rA   = tid >> 2;          // 0..63
    const int soff = (((tid & 3) ^ ((rA >> 1) & 3)) << 4);
    const size_t lda2 = (size_t)K * 2;
    const char* sA = (const char*)A  + (size_t)(m0 + rA) * lda2 + soff;
    const char* sB = (const char*)Bm + (size_t)(n0 + rA) * lda2 + soff;

    auto STAGE = [&](int bf, int kt) {
        char* dA = smem + bf * BUF + wid * 1024;
        __builtin_amdgcn_global_load_lds(GAS1(sA + (size_t)kt * 64), LAS3(dA), 16, 0, 0);
        __builtin_amdgcn_global_load_lds(GAS1(sA + 64 * lda2 + (size_t)kt * 64),
                                         LAS3(dA + 4096), 16, 0, 0);
        char* dB = smem + bf * BUF + 8192 + wid * 1024;
        __builtin_amdgcn_global_load_lds(GAS1(sB + (size_t)kt * 64), LAS3(dB), 16, 0, 0);
        __builtin_amdgcn_global_load_lds(GAS1(sB + 64 * lda2 + (size_t)kt * 64),
                                         LAS3(dB + 4096), 16, 0, 0);
    };

    f32x4 acc[4][4];
    #pragma unroll
    for (int i = 0; i < 4; ++i)
        #pragma unroll
        for (int j = 0; j < 4; ++j) acc[i][j] = (f32x4){0.f, 0.f, 0.f, 0.f};

    const int NT = K >> 5;              // 32

    STAGE(0, 0); STAGE(1, 1);
    asm volatile("s_waitcnt vmcnt(4)" ::: "memory");
    __builtin_amdgcn_s_barrier();

    int cur = 0, pb = 2;
    for (int t = 0; t < NT; ++t) {
        if (t + 2 < NT) STAGE(pb, t + 2);
        const char* base = smem + cur * BUF;
        bf16x8 av[4], bv[4];
        #pragma unroll
        for (int i = 0; i < 4; ++i) {
            av[i] = *(const bf16x8*)(base + offA0 + i * 1024);
            bv[i] = *(const bf16x8*)(base + offB0 + i * 1024);
        }
        __builtin_amdgcn_s_setprio(1);
        #pragma unroll
        for (int mi = 0; mi < 4; ++mi)
            #pragma unroll
            for (int ni = 0; ni < 4; ++ni)
                acc[mi][ni] = __builtin_amdgcn_mfma_f32_16x16x32_bf16(
                    av[mi], bv[ni], acc[mi][ni], 0, 0, 0);
        __builtin_amdgcn_s_setprio(0);
        if (t + 1 < NT) {
            if (t + 2 < NT) asm volatile("s_waitcnt vmcnt(4)" ::: "memory");
            else            asm volatile("s_waitcnt vmcnt(0)" ::: "memory");
            __builtin_amdgcn_s_barrier();
        }
        cur = (cur == 2) ? 0 : cur + 1;
        pb  = (pb  == 2) ? 0 : pb  + 1;
    }

    if (bx < 16) {
        // U epilogue: silu(acc + bu) -> row-major (nb, d1)
        const int fq = c * 4;
        #pragma unroll
        for (int mi = 0; mi < 4; ++mi) {
            #pragma unroll
            for (int ni = 0; ni < 4; ++ni) {
                const int gn = n0 + wrn + ni * 16 + frow;
                #pragma unroll
                for (int j = 0; j < 4; ++j) {
                    const int gm = m0 + wrm + mi * 16 + fq + j;
                    float v = acc[mi][ni][j] + bbu[gn];
                    v = v / (1.f + __expf(-v));
                    Ub[(size_t)gm * D1Q + gn] = (bf16_t)v;
                }
            }
        }
        return;
    }

    // V epilogue: silu(acc + bv) -> (h, b, hd, t).  Single-pass LDS transpose:
    // chunk[hd_local:128][b:4][t:32], row stride 136 elems (pad 8).
    // m_local = wrm + mi*16 + c*4 + j  ->  t_local = wm*16 + mi*4 + c, b = j.
    {
        const int bxv = bx - 16;
        const int hh  = bxv >> 1;
        const int hd0 = (bxv & 1) * 128;
        const int n0v = bxv * 128;
        float bb[4];
        #pragma unroll
        for (int ni = 0; ni < 4; ++ni) bb[ni] = bbv[n0v + wrn + ni * 16 + frow];

        __syncthreads();
        bf16_t* chunk = (bf16_t*)smem;
        const int tl0 = wm * 16 + c;
        #pragma unroll
        for (int mi = 0; mi < 4; ++mi) {
            #pragma unroll
            for (int ni = 0; ni < 4; ++ni) {
                const int hdl = wrn + ni * 16 + frow;
                #pragma unroll
                for (int j = 0; j < 4; ++j) {   // j == b
                    float v = acc[mi][ni][j] + bb[ni];
                    v = v / (1.f + __expf(-v));
                    chunk[hdl * 136 + j * 32 + tl0 + mi * 4] = (bf16_t)v;
                }
            }
        }
        __syncthreads();
        const int nl  = lane & 31;
        const int bs  = lane >> 5;
        const int hdl = wid * 32 + nl;
        const int t0  = m0 >> 2;            // 32-t run start
        #pragma unroll
        for (int bi = 0; bi < 2; ++bi) {
            const int b2 = bs * 2 + bi;
            const bf16_t* src = chunk + hdl * 136 + b2 * 32;
            bf16_t* dst = Vt + (((size_t)hh * 4 + b2) * 256 + hd0 + hdl) * (size_t)LQ + t0;
            #pragma unroll
            for (int u = 0; u < 4; ++u)
                *(bf16x8*)(dst + u * 8) = *(const bf16x8*)(src + u * 8);
        }
    }
}

// ---------------------------------------------------------------- Toeplitz GEMM
// Per head h: out[t,n] = sum_s T_h[t,s] * VT[h][n][s], n = b*256+hd (N=1024).
// Heavy-first 1024 blocks; causal NT = 4*m_blk+4.
__global__ __launch_bounds__(256, 3) void gemm_toep(
    const bf16_t* __restrict__ VT, const bf16_t* __restrict__ Atiles,
    const bf16_t* __restrict__ U, bf16_t* __restrict__ O)
{
    constexpr int BUF = 16384;
    __shared__ alignas(16) char smem[3 * BUF];

    const int bid   = blockIdx.x;          // 0..1023
    const int m_blk = 15 - (bid >> 6);     // heavy-first
    const int sub   = bid & 63;
    const int h     = sub >> 3;
    const int n0    = (sub & 7) * 128;
    const int m0    = m_blk * 128;

    const int tid  = threadIdx.x;
    const int wid  = tid >> 6;
    const int lane = tid & 63;
    const int frow = lane & 15;
    const int c    = lane >> 4;
    const int wm = wid >> 1, wn = wid & 1;
    const int wrm = wm * 64, wrn = wn * 64;

    const int g = (frow >> 1) & 3;
    const int offA0 = (wrm + frow) * 64 + ((c ^ g) << 4);
    const int offB0 = 8192 + (wrn + frow) * 64 + ((c ^ g) << 4);

    const int rA   = tid >> 2;          // 0..63
    const int soff = (((tid & 3) ^ ((rA >> 1) & 3)) << 4);
    const char* Ah = (const char*)Atiles + (size_t)h * 64 * 8192;
    const size_t ldb = (size_t)LQ * 2;
    const char* sB = (const char*)VT + ((size_t)h * 1024 + n0 + rA) * ldb + soff;

    auto STAGE = [&](int bf, int kt) {
        const int q = 4 * m_blk + 3 - kt;
        const char* s = Ah + (size_t)q * 8192 + (size_t)rA * 64 + soff;
        char* dA = smem + bf * BUF + wid * 1024;
        __builtin_amdgcn_global_load_lds(GAS1(s), LAS3(dA), 16, 0, 0);
        __builtin_amdgcn_global_load_lds(GAS1(s + 4096), LAS3(dA + 4096), 16, 0, 0);
        char* dB = smem + bf * BUF + 8192 + wid * 1024;
        __builtin_amdgcn_global_load_lds(GAS1(sB + (size_t)kt * 64), LAS3(dB), 16, 0, 0);
        __builtin_amdgcn_global_load_lds(GAS1(sB + 64 * ldb + (size_t)kt * 64),
                                         LAS3(dB + 4096), 16, 0, 0);
    };

    f32x4 acc[4][4];
    #pragma unroll
    for (int i = 0; i < 4; ++i)
        #pragma unroll
        for (int j = 0; j < 4; ++j) acc[i][j] = (f32x4){0.f, 0.f, 0.f, 0.f};

    const int NT = 4 * m_blk + 4;          // >= 4

    STAGE(0, 0); STAGE(1, 1);
    asm volatile("s_waitcnt vmcnt(4)" ::: "memory");
    __builtin_amdgcn_s_barrier();

    int cur = 0, pb = 2;
    for (int t = 0; t < NT; ++t) {
        if (t + 2 < NT) STAGE(pb, t + 2);
        const char* base = smem + cur * BUF;
        bf16x8 av[4], bv[4];
        #pragma unroll
        for (int i = 0; i < 4; ++i) {
            av[i] = *(const bf16x8*)(base + offA0 + i * 1024);
            bv[i] = *(const bf16x8*)(base + offB0 + i * 1024);
        }
        __builtin_amdgcn_s_setprio(1);
        #pragma unroll
        for (int mi = 0; mi < 4; ++mi)
            #pragma unroll
            for (int ni = 0; ni < 4; ++ni)
                acc[mi][ni] = __builtin_amdgcn_mfma_f32_16x16x32_bf16(
                    av[mi], bv[ni], acc[mi][ni], 0, 0, 0);
        __builtin_amdgcn_s_setprio(0);
        if (t + 1 < NT) {
            if (t + 2 < NT) asm volatile("s_waitcnt vmcnt(4)" ::: "memory");
            else            asm volatile("s_waitcnt vmcnt(0)" ::: "memory");
            __builtin_amdgcn_s_barrier();
        }
        cur = (cur == 2) ? 0 : cur + 1;
        pb  = (pb  == 2) ? 0 : pb  + 1;
    }

    // epilogue: gate with U, scatter to (t*4+b, h*256+hd)
    const int fq = c * 4;
    #pragma unroll
    for (int mi = 0; mi < 4; ++mi) {
        #pragma unroll
        for (int ni = 0; ni < 4; ++ni) {
            const int nn = n0 + wrn + ni * 16 + frow;   // 0..1023
            const int b  = nn >> 8, hd = nn & 255;
            #pragma unroll
            for (int j = 0; j < 4; ++j) {
                const int t = m0 + wrm + mi * 16 + fq + j;
                const size_t idx = ((size_t)t * BQ + b) * D1Q + h * HDQ + hd;
                const float uval = (float)U[idx];
                O[idx] = (bf16_t)(uval * acc[mi][ni][j]);
            }
        }
    }
}

// ---------------------------------------------------------------- final GEMM
__global__ __launch_bounds__(256, 3) void gemm_fin(
    const bf16_t* __restrict__ A, const bf16_t* __restrict__ Bm,
    const float* __restrict__ bias, const float* __restrict__ res,
    float* __restrict__ Cf)
{
    constexpr int K = D1Q, N = EQ;
    constexpr int BUF = 16384;
    __shared__ alignas(16) char smem[3 * BUF];

    const int nwg   = gridDim.x * gridDim.y;
    const int bid0  = blockIdx.y * gridDim.x + blockIdx.x;
    const int chunkw = nwg >> 3;
    const int sb    = (bid0 & 7) * chunkw + (bid0 >> 3);
    const int bx    = sb % gridDim.x;
    const int by    = sb / gridDim.x;

    const int tid  = threadIdx.x;
    const int wid  = tid >> 6;
    const int lane = tid & 63;
    const int frow = lane & 15;
    const int c    = lane >> 4;
    const int m0 = by * 128;
    const int n0 = bx * 128;
    const int wm = wid >> 1, wn = wid & 1;
    const int wrm = wm * 64, wrn = wn * 64;

    const int g = (frow >> 1) & 3;
    const int offA0 = (wrm + frow) * 64 + ((c ^ g) << 4);
    const int offB0 = 8192 + (wrn + frow) * 64 + ((c ^ g) << 4);

    const int rA   = tid >> 2;          // 0..63
    const int soff = (((tid & 3) ^ ((rA >> 1) & 3)) << 4);
    const size_t lda2 = (size_t)K * 2;
    const char* sA = (const char*)A  + (size_t)(m0 + rA) * lda2 + soff;
    const char* sB = (const char*)Bm + (size_t)(n0 + rA) * lda2 + soff;

    auto STAGE = [&](int bf, int kt) {
        char* dA = smem + bf * BUF + wid * 1024;
        __builtin_amdgcn_global_load_lds(GAS1(sA + (size_t)kt * 64), LAS3(dA), 16, 0, 0);
        __builtin_amdgcn_global_load_lds(GAS1(sA + 64 * lda2 + (size_t)kt * 64),
                                         LAS3(dA + 4096), 16, 0, 0);
        char* dB = smem + bf * BUF + 8192 + wid * 1024;
        __builtin_amdgcn_global_load_lds(GAS1(sB + (size_t)kt * 64), LAS3(dB), 16, 0, 0);
        __builtin_amdgcn_global_load_lds(GAS1(sB + 64 * lda2 + (size_t)kt * 64),
                                         LAS3(dB + 4096), 16, 0, 0);
    };

    f32x4 acc[4][4];
    #pragma unroll
    for (int i = 0; i < 4; ++i)
        #pragma unroll
        for (int j = 0; j < 4; ++j) acc[i][j] = (f32x4){0.f, 0.f, 0.f, 0.f};

    const int NT = K >> 5;              // 64

    STAGE(0, 0); STAGE(1, 1);
    asm volatile("s_waitcnt vmcnt(4)" ::: "memory");
    __builtin_amdgcn_s_barrier();

    int cur = 0, pb = 2;
    for (int t = 0; t < NT; ++t) {
        if (t + 2 < NT) STAGE(pb, t + 2);
        const char* base = smem + cur * BUF;
        bf16x8 av[4], bv[4];
        #pragma unroll
        for (int i = 0; i < 4; ++i) {
            av[i] = *(const bf16x8*)(base + offA0 + i * 1024);
            bv[i] = *(const bf16x8*)(base + offB0 + i * 1024);
        }
        __builtin_amdgcn_s_setprio(1);
        #pragma unroll
        for (int mi = 0; mi < 4; ++mi)
            #pragma unroll
            for (int ni = 0; ni < 4; ++ni)
                acc[mi][ni] = __builtin_amdgcn_mfma_f32_16x16x32_bf16(
                    av[mi], bv[ni], acc[mi][ni], 0, 0, 0);
        __builtin_amdgcn_s_setprio(0);
        if (t + 1 < NT) {
            if (t + 2 < NT) asm volatile("s_waitcnt vmcnt(4)" ::: "memory");
            else            asm volatile("s_waitcnt vmcnt(0)" ::: "memory");
            __builtin_amdgcn_s_barrier();
        }
        cur = (cur == 2) ? 0 : cur + 1;
        pb  = (pb  == 2) ? 0 : pb  + 1;
    }

    const int fq = c * 4;
    #pragma unroll
    for (int mi = 0; mi < 4; ++mi) {
        #pragma unroll
        for (int ni = 0; ni < 4; ++ni) {
            const int gn = n0 + wrn + ni * 16 + frow;
            #pragma unroll
            for (int j = 0; j < 4; ++j) {
                const int gm = m0 + wrm + mi * 16 + fq + j;
                Cf[(size_t)gm * N + gn] =
                    acc[mi][ni][j] + bias[gn] + res[(size_t)gm * N + gn];
            }
        }
    }
}

// ---------------------------------------------------------------- launch

extern "C" void kernel_launch(void* const* d_in, const int* in_sizes, int n_in,
                              void* d_out, int out_size, void* d_ws, size_t ws_size,
                              hipStream_t stream)
{
    const float* x    = (const float*)d_in[0];
    const float* Wu   = (const float*)d_in[1];
    const float* bu   = (const float*)d_in[2];
    const float* Wv   = (const float*)d_in[3];
    const float* bv   = (const float*)d_in[4];
    const float* Wo   = (const float*)d_in[5];
    const float* bo   = (const float*)d_in[6];
    const float* zero = (const float*)d_in[7];
    const float* pos  = (const float*)d_in[8];
    float* out = (float*)d_out;

    char* ws = (char*)d_ws;
    size_t off = 0;
    auto alloc = [&](size_t bytes) {
        char* p = ws + off;
        off += (bytes + 255) & ~(size_t)255;
        return p;
    };
    bf16_t* xn     = (bf16_t*)alloc((size_t)NBQ * EQ * 2);
    bf16_t* Wub    = (bf16_t*)alloc((size_t)D1Q * EQ * 2);    // | contiguous:
    bf16_t* Wvb    = (bf16_t*)alloc((size_t)D1Q * EQ * 2);    // | B = [Wu; Wv]
    bf16_t* Wob    = (bf16_t*)alloc((size_t)EQ * D1Q * 2);
    bf16_t* Atiles = (bf16_t*)alloc((size_t)HQ * 64 * 4096 * 2);  // 4 MB
    bf16_t* Ub     = (bf16_t*)alloc((size_t)NBQ * D1Q * 2);
    bf16_t* VTb    = (bf16_t*)alloc((size_t)NBQ * D1Q * 2);   // (h,b,hd,t)
    bf16_t* Ob     = (bf16_t*)alloc((size_t)NBQ * D1Q * 2);

    convert_kernel<<<8192, 256, 0, stream>>>(Wu, Wv, Wo, Wub, Wvb, Wob);
    build_toep_tiles<<<dim3(64, 8), 256, 0, stream>>>(zero, pos, Atiles);
    rmsnorm_kernel<<<NBQ, 256, 0, stream>>>(x, xn);

    // merged U+V: M=8192, N=4096, K=1024 — 128x128 tiles, 2048 blocks, 3/CU
    dim3 g1(32, NBQ / 128);          // (32, 64) = 2048 blocks
    gemm_uv<<<g1, 256, 0, stream>>>(xn, Wub, bu, bv, Ub, VTb);

    gemm_toep<<<1024, 256, 0, stream>>>(VTb, Atiles, Ub, Ob);

    // final: M=8192, N=1024, K=2048 — 128x128 tiles, 512 blocks, 3/CU
    dim3 g2(EQ / 128, NBQ / 128);    // (8, 64)
    gemm_fin<<<g2, 256, 0, stream>>>(Ob, Wob, bo, x, out);
}

// Round 13
// 197.767 us; speedup vs baseline: 1.0966x; 1.0966x over previous
//
#include <hip/hip_runtime.h>
#include <cstdint>
#include <cstddef>

#define LQ   2048
#define BQ   4
#define EQ   1024
#define HQ   8
#define D1Q  2048
#define HDQ  256
#define NBQ  (LQ*BQ)   // 8192 rows in (n,b) layout

typedef __bf16 bf16_t;
typedef __bf16 bf16x8 __attribute__((ext_vector_type(8)));
typedef __bf16 bf16x4 __attribute__((ext_vector_type(4)));
typedef float  f32x4  __attribute__((ext_vector_type(4)));

#define GAS1(p) ((const __attribute__((address_space(1))) void*)(p))
#define LAS3(p) ((__attribute__((address_space(3))) void*)(p))

// ---------------------------------------------------------------- utilities

__global__ __launch_bounds__(256) void convert_kernel(
    const float* __restrict__ Wu, const float* __restrict__ Wv,
    const float* __restrict__ Wo,
    bf16_t* __restrict__ Wub, bf16_t* __restrict__ Wvb,
    bf16_t* __restrict__ Wob)
{
    const size_t i = (size_t)blockIdx.x * 256 + threadIdx.x;
    if (i < (size_t)D1Q * EQ) {
        Wub[i] = (bf16_t)Wu[i];
        Wvb[i] = (bf16_t)Wv[i];
        Wob[i] = (bf16_t)Wo[i];
    }
}

// Toeplitz A-tiles, 128 rows x 64 cols (BK=64), diag offset (q-1)*64.
__global__ __launch_bounds__(256) void build_toep_tiles2(
    const float* __restrict__ zero, const float* __restrict__ pos,
    bf16_t* __restrict__ At)
{
    const int q = blockIdx.x;        // 0..31
    const int h = blockIdx.y;        // 0..7
    const int doff = (q - 1) * 64;
    const int tid = threadIdx.x;
    bf16_t* dst = At + ((size_t)h * 32 + q) * 8192;
    const int r  = tid >> 1;
    const int c0 = (tid & 1) * 32;
    bf16_t vals[32];
    #pragma unroll
    for (int j = 0; j < 32; ++j) {
        const int d = doff + r - (c0 + j);
        float v = 0.f;
        if (d == 0) v = zero[h];
        else if (d > 0 && d < LQ) v = pos[(size_t)h * (LQ - 1) + d - 1];
        vals[j] = (bf16_t)v;
    }
    #pragma unroll
    for (int qq = 0; qq < 4; ++qq)
        *(bf16x8*)(dst + r * 64 + c0 + qq * 8) = *(bf16x8*)(vals + qq * 8);
}

__global__ __launch_bounds__(256) void rmsnorm_kernel(
    const float* __restrict__ x, bf16_t* __restrict__ xn)
{
    const int row = blockIdx.x;           // 0..8191
    const int tid = threadIdx.x;
    const float4 v = ((const float4*)(x + (size_t)row * EQ))[tid];
    float ss = v.x*v.x + v.y*v.y + v.z*v.z + v.w*v.w;
    #pragma unroll
    for (int m = 32; m >= 1; m >>= 1) ss += __shfl_xor(ss, m, 64);
    __shared__ float red[4];
    const int wid = tid >> 6, lane = tid & 63;
    if (lane == 0) red[wid] = ss;
    __syncthreads();
    const float tot = red[0] + red[1] + red[2] + red[3];
    const float inv = 1.f / (sqrtf(tot * (1.f / EQ)) + 1e-8f);
    bf16x4 o;
    o[0] = (bf16_t)(v.x * inv); o[1] = (bf16_t)(v.y * inv);
    o[2] = (bf16_t)(v.z * inv); o[3] = (bf16_t)(v.w * inv);
    *(bf16x4*)(xn + (size_t)row * EQ + tid * 4) = o;
}

// ---------------------------------------------------------------- merged U+V GEMM
// R11 geometry (best measured: low traffic + 2 blocks/CU) + counted vmcnt:
// BM=256, BN=128, BK=32, 512 threads = 8 waves (4M x 2N), wave tile 64x64.
// LDS = 3 x (A 16K + B 8K) = 72 KB -> 2 blocks/CU (144 <= 160 KB).
// Prefetch distance 2; 3 loads/thread/stage; boundary vmcnt(3), never 0
// until the tail.  Conflict-free swizzle (R7/R8-verified, 0 conflicts).
// B = [Wu; Wv]: bx<16 -> U (silu, row-major); bx>=16 -> V (silu, (h,b,hd,t)
// via pair-wave LDS transpose, full 64-B t-runs) — epilogues verbatim R11.
__global__ __launch_bounds__(512, 2) void gemm_uv(
    const bf16_t* __restrict__ A, const bf16_t* __restrict__ Bm,
    const float* __restrict__ bbu, const float* __restrict__ bbv,
    bf16_t* __restrict__ Ub, bf16_t* __restrict__ Vt)
{
    constexpr int K = EQ;            // 1024
    constexpr int BUF = 24576;       // A 16K + B 8K
    __shared__ alignas(16) char smem[3 * BUF];   // 72 KB

    // XCD-chunked bijective swizzle (nwg = 1024)
    const int nwg   = gridDim.x * gridDim.y;
    const int bid0  = blockIdx.y * gridDim.x + blockIdx.x;
    const int chunkw = nwg >> 3;
    const int sb    = (bid0 & 7) * chunkw + (bid0 >> 3);
    const int bx    = sb % gridDim.x;
    const int by    = sb / gridDim.x;

    const int tid  = threadIdx.x;
    const int wid  = tid >> 6;          // 0..7
    const int lane = tid & 63;
    const int frow = lane & 15;
    const int c    = lane >> 4;
    const int m0 = by * 256;
    const int n0 = bx * 128;
    const int wm = wid >> 1, wn = wid & 1;
    const int wrm = wm * 64, wrn = wn * 64;

    const int g = (frow >> 1) & 3;
    const int offA0 = (wrm + frow) * 64 + ((c ^ g) << 4);
    const int offB0 = 16384 + (wrn + frow) * 64 + ((c ^ g) << 4);

    const int rA   = tid >> 2;          // 0..127
    const int soff = (((tid & 3) ^ ((rA >> 1) & 3)) << 4);
    const size_t lda2 = (size_t)K * 2;
    const char* sA = (const char*)A  + (size_t)(m0 + rA) * lda2 + soff;
    const char* sB = (const char*)Bm + (size_t)(n0 + rA) * lda2 + soff;

    auto STAGE = [&](int bf, int kt) {   // 3 loads / thread
        char* dA = smem + bf * BUF + wid * 1024;
        __builtin_amdgcn_global_load_lds(GAS1(sA + (size_t)kt * 64), LAS3(dA), 16, 0, 0);
        __builtin_amdgcn_global_load_lds(GAS1(sA + 128 * lda2 + (size_t)kt * 64),
                                         LAS3(dA + 8192), 16, 0, 0);
        char* dB = smem + bf * BUF + 16384 + wid * 1024;
        __builtin_amdgcn_global_load_lds(GAS1(sB + (size_t)kt * 64), LAS3(dB), 16, 0, 0);
    };

    f32x4 acc[4][4];
    #pragma unroll
    for (int i = 0; i < 4; ++i)
        #pragma unroll
        for (int j = 0; j < 4; ++j) acc[i][j] = (f32x4){0.f, 0.f, 0.f, 0.f};

    const int NT = K >> 5;              // 32

    STAGE(0, 0); STAGE(1, 1);
    asm volatile("s_waitcnt vmcnt(3)" ::: "memory");   // tile0 resident
    __builtin_amdgcn_s_barrier();

    int cur = 0, pb = 2;
    for (int t = 0; t < NT; ++t) {
        if (t + 2 < NT) STAGE(pb, t + 2);
        const char* base = smem + cur * BUF;
        bf16x8 av[4], bv[4];
        #pragma unroll
        for (int i = 0; i < 4; ++i) {
            av[i] = *(const bf16x8*)(base + offA0 + i * 1024);
            bv[i] = *(const bf16x8*)(base + offB0 + i * 1024);
        }
        __builtin_amdgcn_s_setprio(1);
        #pragma unroll
        for (int mi = 0; mi < 4; ++mi)
            #pragma unroll
            for (int ni = 0; ni < 4; ++ni)
                acc[mi][ni] = __builtin_amdgcn_mfma_f32_16x16x32_bf16(
                    av[mi], bv[ni], acc[mi][ni], 0, 0, 0);
        __builtin_amdgcn_s_setprio(0);
        if (t + 1 < NT) {
            if (t + 2 < NT) asm volatile("s_waitcnt vmcnt(3)" ::: "memory");
            else            asm volatile("s_waitcnt vmcnt(0)" ::: "memory");
            __builtin_amdgcn_s_barrier();
        }
        cur = (cur == 2) ? 0 : cur + 1;
        pb  = (pb  == 2) ? 0 : pb  + 1;
    }

    if (bx < 16) {
        // U epilogue: silu(acc + bu) -> row-major (nb, d1)
        const int fq = c * 4;
        #pragma unroll
        for (int mi = 0; mi < 4; ++mi) {
            #pragma unroll
            for (int ni = 0; ni < 4; ++ni) {
                const int gn = n0 + wrn + ni * 16 + frow;
                #pragma unroll
                for (int j = 0; j < 4; ++j) {
                    const int gm = m0 + wrm + mi * 16 + fq + j;
                    float v = acc[mi][ni][j] + bbu[gn];
                    v = v / (1.f + __expf(-v));
                    Ub[(size_t)gm * D1Q + gn] = (bf16_t)v;
                }
            }
        }
        return;
    }

    // V epilogue (verbatim R11, passing): silu(acc+bv) -> (h,b,hd,t).
    {
        const int n0v = n0 - 2048;
        const int hh  = n0v >> 8;
        const int hdb = (n0v & 255) + wrn;
        float bb[4];
        #pragma unroll
        for (int ni = 0; ni < 4; ++ni) bb[ni] = bbv[n0v + wrn + ni * 16 + frow];

        bf16_t* chunk = (bf16_t*)smem + wn * 8448;
        #pragma unroll
        for (int p = 0; p < 2; ++p) {          // ni-pair halves
            __syncthreads();
            #pragma unroll
            for (int mi = 0; mi < 4; ++mi) {
                #pragma unroll
                for (int nio = 0; nio < 2; ++nio) {
                    const int ni = p * 2 + nio;
                    const int nl = nio * 16 + frow;
                    const int tl = wm * 16 + mi * 4 + c;
                    #pragma unroll
                    for (int j = 0; j < 4; ++j) {   // j == b
                        float v = acc[mi][ni][j] + bb[ni];
                        v = v / (1.f + __expf(-v));
                        chunk[nl * 264 + j * 64 + tl] = (bf16_t)v;
                    }
                }
            }
            __syncthreads();
            const int nl    = lane & 31;
            const int thalf = lane >> 5;
            const int b2    = wm;
            const int hd    = hdb + p * 32 + nl;
            const int t0    = (m0 >> 2) + thalf * 32;
            const bf16_t* src = chunk + nl * 264 + b2 * 64 + thalf * 32;
            bf16_t* dst = Vt + (((size_t)hh * 4 + b2) * 256 + hd) * (size_t)LQ + t0;
            #pragma unroll
            for (int u = 0; u < 4; ++u)
                *(bf16x8*)(dst + u * 8) = *(const bf16x8*)(src + u * 8);
        }
    }
}

// ---------------------------------------------------------------- phase primitive
template<int KK, int MH, int WAITN, bool LDB, int MI_, typename F>
__device__ __forceinline__ void phase_op(const char* base, int offA0, int offB0,
    bf16x8 (&bv)[4], f32x4 (&acc)[MI_][4], F&& stage)
{
    bf16x8 av[4];
    #pragma unroll
    for (int i = 0; i < 4; ++i)
        av[i] = *(const bf16x8*)(base + (offA0 ^ (KK << 6)) + (MH * 4 + i) * 2048);
    if constexpr (LDB) {
        #pragma unroll
        for (int i = 0; i < 4; ++i)
            bv[i] = *(const bf16x8*)(base + (offB0 ^ (KK << 6)) + i * 2048);
    }
    stage();
    __builtin_amdgcn_s_barrier();
    __builtin_amdgcn_s_setprio(1);
    #pragma unroll
    for (int i = 0; i < 4; ++i)
        #pragma unroll
        for (int ni = 0; ni < 4; ++ni)
            acc[MH * 4 + i][ni] = __builtin_amdgcn_mfma_f32_16x16x32_bf16(
                av[i], bv[ni], acc[MH * 4 + i][ni], 0, 0, 0);
    __builtin_amdgcn_s_setprio(0);
    if constexpr (WAITN >= 0)
        asm volatile("s_waitcnt vmcnt(%0)" :: "i"(WAITN) : "memory");
    __builtin_amdgcn_s_barrier();
}

// ---------------------------------------------------------------- 4-phase 128x256 GEMM (final)
// (verbatim R8/R10 — best measured fin)
__global__ __launch_bounds__(512, 1) void gemm_fin(
    const bf16_t* __restrict__ A, const bf16_t* __restrict__ Bm,
    const float* __restrict__ bias, const float* __restrict__ res,
    float* __restrict__ Cf)
{
    constexpr int K = D1Q, N = EQ;
    constexpr int BSTRIDE = 49152;            // A 16K + B 32K
    __shared__ alignas(16) char smem[3 * BSTRIDE];

    const int nwg   = gridDim.x * gridDim.y;
    const int bid0  = blockIdx.y * gridDim.x + blockIdx.x;
    const int chunkw = nwg >> 3;
    const int sb    = (bid0 & 7) * chunkw + (bid0 >> 3);
    const int bx    = sb % gridDim.x;
    const int by    = sb / gridDim.x;

    const int tid  = threadIdx.x;
    const int wid  = tid >> 6;
    const int lane = tid & 63;
    const int frow = lane & 15;
    const int c    = lane >> 4;
    const int m0 = by * 128;
    const int n0 = bx * 256;
    const int wrm = (wid >> 2) * 64;
    const int wrn = (wid & 3) * 64;

    const int g = frow & 7;
    const int offA0 = (wrm + frow) * 128 + ((c ^ g) << 4);
    const int offB0 = 16384 + (wrn + frow) * 128 + ((c ^ g) << 4);

    const int rl = tid >> 3;
    const int ls = (tid & 7) ^ (rl & 7);
    const size_t lda2 = (size_t)K * 2;
    const char* sA = (const char*)A  + (size_t)(m0 + rl) * lda2 + ls * 16;
    const char* sB = (const char*)Bm + (size_t)(n0 + rl) * lda2 + ls * 16;

    auto SH_A = [&](int bf, int kt) {
        const char* s = sA + (size_t)kt * 128;
        char* d = smem + bf * BSTRIDE + wid * 1024;
        __builtin_amdgcn_global_load_lds(GAS1(s), LAS3(d), 16, 0, 0);
        __builtin_amdgcn_global_load_lds(GAS1(s + 64 * lda2), LAS3(d + 8192), 16, 0, 0);
    };
    auto SH_B = [&](int bf, int hf, int kt) {
        const char* s = sB + (size_t)(hf * 128) * lda2 + (size_t)kt * 128;
        char* d = smem + bf * BSTRIDE + 16384 + hf * 16384 + wid * 1024;
        __builtin_amdgcn_global_load_lds(GAS1(s), LAS3(d), 16, 0, 0);
        __builtin_amdgcn_global_load_lds(GAS1(s + 64 * lda2), LAS3(d + 8192), 16, 0, 0);
    };

    f32x4 acc[4][4];
    #pragma unroll
    for (int i = 0; i < 4; ++i)
        #pragma unroll
        for (int j = 0; j < 4; ++j) acc[i][j] = (f32x4){0.f, 0.f, 0.f, 0.f};
    bf16x8 bv[4];

    const int NT = K >> 6;                    // 32

    SH_A(0, 0); SH_B(0, 0, 0); SH_B(0, 1, 0);
    SH_A(1, 1); SH_B(1, 0, 1); SH_B(1, 1, 1);
    asm volatile("s_waitcnt vmcnt(6)" ::: "memory");
    __builtin_amdgcn_s_barrier();

    int cur = 0, pb = 2;
    for (int t = 0; t < NT; ++t) {
        const char* base = smem + cur * BSTRIDE;
        const int t2 = t + 2;
        const bool pf = t2 < NT;
        phase_op<0,0,-1,true>(base, offA0, offB0, bv, acc,
            [&]{ if (pf) { SH_A(pb, t2); SH_B(pb, 0, t2); } });
        phase_op<1,0, 6,true>(base, offA0, offB0, bv, acc,
            [&]{ if (pf) SH_B(pb, 1, t2); });
        cur = (cur == 2) ? 0 : cur + 1;
        pb  = (pb  == 2) ? 0 : pb  + 1;
    }

    const int fq = c * 4;
    #pragma unroll
    for (int mi = 0; mi < 4; ++mi) {
        #pragma unroll
        for (int ni = 0; ni < 4; ++ni) {
            const int gn = n0 + wrn + ni * 16 + frow;
            #pragma unroll
            for (int j = 0; j < 4; ++j) {
                const int gm = m0 + wrm + mi * 16 + fq + j;
                Cf[(size_t)gm * N + gn] =
                    acc[mi][ni][j] + bias[gn] + res[(size_t)gm * N + gn];
            }
        }
    }
}

// ---------------------------------------------------------------- 4-phase Toeplitz GEMM
// (verbatim R8/R10 — best measured toep)
__global__ __launch_bounds__(512, 1) void gemm_toep4p(
    const bf16_t* __restrict__ VT, const bf16_t* __restrict__ Atl,
    const bf16_t* __restrict__ U, bf16_t* __restrict__ O)
{
    constexpr int BSTRIDE = 49152;
    __shared__ alignas(16) char smem[3 * BSTRIDE];

    const int bid   = blockIdx.x;          // 0..511
    const int m_blk = 15 - (bid >> 5);     // heavy-first
    const int sub   = bid & 31;
    const int h     = sub >> 2;
    const int n0    = (sub & 3) * 256;
    const int m0    = m_blk * 128;

    const int tid  = threadIdx.x;
    const int wid  = tid >> 6;
    const int lane = tid & 63;
    const int frow = lane & 15;
    const int c    = lane >> 4;
    const int wrm  = (wid >> 2) * 64;
    const int wrn  = (wid & 3) * 64;

    const int g = frow & 7;
    const int offA0 = (wrm + frow) * 128 + ((c ^ g) << 4);
    const int offB0 = 16384 + (wrn + frow) * 128 + ((c ^ g) << 4);

    const int rl = tid >> 3;
    const int ls = (tid & 7) ^ (rl & 7);
    const char* Ah = (const char*)Atl + (size_t)h * 32 * 16384;
    const size_t ldb = (size_t)LQ * 2;
    const char* sB = (const char*)VT + ((size_t)h * 1024 + n0 + rl) * ldb + ls * 16;

    auto SH_A = [&](int bf, int kt) {
        const int q = 2 * m_blk - kt + 1;
        const char* s = Ah + (size_t)q * 16384 + (size_t)rl * 128 + ls * 16;
        char* d = smem + bf * BSTRIDE + wid * 1024;
        __builtin_amdgcn_global_load_lds(GAS1(s), LAS3(d), 16, 0, 0);
        __builtin_amdgcn_global_load_lds(GAS1(s + 64 * 128), LAS3(d + 8192), 16, 0, 0);
    };
    auto SH_B = [&](int bf, int hf, int kt) {
        const char* s = sB + (size_t)(hf * 128) * ldb + (size_t)kt * 128;
        char* d = smem + bf * BSTRIDE + 16384 + hf * 16384 + wid * 1024;
        __builtin_amdgcn_global_load_lds(GAS1(s), LAS3(d), 16, 0, 0);
        __builtin_amdgcn_global_load_lds(GAS1(s + 64 * ldb), LAS3(d + 8192), 16, 0, 0);
    };

    f32x4 acc[4][4];
    #pragma unroll
    for (int i = 0; i < 4; ++i)
        #pragma unroll
        for (int j = 0; j < 4; ++j) acc[i][j] = (f32x4){0.f, 0.f, 0.f, 0.f};
    bf16x8 bv[4];

    const int NT = 2 * m_blk + 2;          // causal BK=64 tiles (even)

    SH_A(0, 0); SH_B(0, 0, 0); SH_B(0, 1, 0);
    SH_A(1, 1); SH_B(1, 0, 1); SH_B(1, 1, 1);
    asm volatile("s_waitcnt vmcnt(6)" ::: "memory");
    __builtin_amdgcn_s_barrier();

    int cur = 0, pb = 2;
    for (int t = 0; t < NT; ++t) {
        const char* base = smem + cur * BSTRIDE;
        const int t2 = t + 2;
        const bool pf = t2 < NT;
        phase_op<0,0,-1,true>(base, offA0, offB0, bv, acc,
            [&]{ if (pf) { SH_A(pb, t2); SH_B(pb, 0, t2); } });
        phase_op<1,0, 6,true>(base, offA0, offB0, bv, acc,
            [&]{ if (pf) SH_B(pb, 1, t2); });
        cur = (cur == 2) ? 0 : cur + 1;
        pb  = (pb  == 2) ? 0 : pb  + 1;
    }

    // epilogue: gate with U and scatter to (t*4+b, h*256+hd)
    const int fq = c * 4;
    #pragma unroll
    for (int mi = 0; mi < 4; ++mi) {
        #pragma unroll
        for (int ni = 0; ni < 4; ++ni) {
            const int nn = n0 + wrn + ni * 16 + frow;   // 0..1023
            const int b  = nn >> 8, hd = nn & 255;
            #pragma unroll
            for (int j = 0; j < 4; ++j) {
                const int t = m0 + wrm + mi * 16 + fq + j;
                const size_t idx = ((size_t)t * BQ + b) * D1Q + h * HDQ + hd;
                const float uval = (float)U[idx];
                O[idx] = (bf16_t)(uval * acc[mi][ni][j]);
            }
        }
    }
}

// ---------------------------------------------------------------- launch

extern "C" void kernel_launch(void* const* d_in, const int* in_sizes, int n_in,
                              void* d_out, int out_size, void* d_ws, size_t ws_size,
                              hipStream_t stream)
{
    const float* x    = (const float*)d_in[0];
    const float* Wu   = (const float*)d_in[1];
    const float* bu   = (const float*)d_in[2];
    const float* Wv   = (const float*)d_in[3];
    const float* bv   = (const float*)d_in[4];
    const float* Wo   = (const float*)d_in[5];
    const float* bo   = (const float*)d_in[6];
    const float* zero = (const float*)d_in[7];
    const float* pos  = (const float*)d_in[8];
    float* out = (float*)d_out;

    char* ws = (char*)d_ws;
    size_t off = 0;
    auto alloc = [&](size_t bytes) {
        char* p = ws + off;
        off += (bytes + 255) & ~(size_t)255;
        return p;
    };
    bf16_t* xn     = (bf16_t*)alloc((size_t)NBQ * EQ * 2);
    bf16_t* Wub    = (bf16_t*)alloc((size_t)D1Q * EQ * 2);    // | contiguous:
    bf16_t* Wvb    = (bf16_t*)alloc((size_t)D1Q * EQ * 2);    // | B = [Wu; Wv]
    bf16_t* Wob    = (bf16_t*)alloc((size_t)EQ * D1Q * 2);
    bf16_t* Atiles = (bf16_t*)alloc((size_t)HQ * 32 * 8192 * 2);  // 4 MB
    bf16_t* Ub     = (bf16_t*)alloc((size_t)NBQ * D1Q * 2);
    bf16_t* VTb    = (bf16_t*)alloc((size_t)NBQ * D1Q * 2);   // (h,b,hd,t)
    bf16_t* Ob     = (bf16_t*)alloc((size_t)NBQ * D1Q * 2);

    convert_kernel<<<8192, 256, 0, stream>>>(Wu, Wv, Wo, Wub, Wvb, Wob);
    build_toep_tiles2<<<dim3(32, 8), 256, 0, stream>>>(zero, pos, Atiles);
    rmsnorm_kernel<<<NBQ, 256, 0, stream>>>(x, xn);

    // merged U+V: M=8192, N=4096, K=1024 — 256x128 tiles, 1024 blocks, 2/CU
    dim3 g1(32, NBQ / 256);          // (32, 32) = 1024 blocks
    gemm_uv<<<g1, 512, 0, stream>>>(xn, Wub, bu, bv, Ub, VTb);

    gemm_toep4p<<<512, 512, 0, stream>>>(VTb, Atiles, Ub, Ob);

    // final: M=8192, N=1024, K=2048 — 128x256 tiles, 256 blocks, 4-phase
    dim3 g2(EQ / 256, NBQ / 128);    // (4, 64)
    gemm_fin<<<g2, 512, 0, stream>>>(Ob, Wob, bo, x, out);
}

// Round 14
// 197.581 us; speedup vs baseline: 1.0977x; 1.0009x over previous
//
#include <hip/hip_runtime.h>
#include <cstdint>
#include <cstddef>

#define LQ   2048
#define BQ   4
#define EQ   1024
#define HQ   8
#define D1Q  2048
#define HDQ  256
#define NBQ  (LQ*BQ)   // 8192 rows in (n,b) layout

typedef __bf16 bf16_t;
typedef __bf16 bf16x8 __attribute__((ext_vector_type(8)));
typedef __bf16 bf16x4 __attribute__((ext_vector_type(4)));
typedef float  f32x4  __attribute__((ext_vector_type(4)));

#define GAS1(p) ((const __attribute__((address_space(1))) void*)(p))
#define LAS3(p) ((__attribute__((address_space(3))) void*)(p))

// ---------------------------------------------------------------- utilities

__global__ __launch_bounds__(256) void convert_kernel(
    const float* __restrict__ Wu, const float* __restrict__ Wv,
    const float* __restrict__ Wo,
    bf16_t* __restrict__ Wub, bf16_t* __restrict__ Wvb,
    bf16_t* __restrict__ Wob)
{
    const size_t i = ((size_t)blockIdx.x * 256 + threadIdx.x) * 4;
    if (i < (size_t)D1Q * EQ) {
        float4 a = *(const float4*)(Wu + i);
        float4 b = *(const float4*)(Wv + i);
        float4 d = *(const float4*)(Wo + i);
        bf16x4 oa, ob, od;
        oa[0]=(bf16_t)a.x; oa[1]=(bf16_t)a.y; oa[2]=(bf16_t)a.z; oa[3]=(bf16_t)a.w;
        ob[0]=(bf16_t)b.x; ob[1]=(bf16_t)b.y; ob[2]=(bf16_t)b.z; ob[3]=(bf16_t)b.w;
        od[0]=(bf16_t)d.x; od[1]=(bf16_t)d.y; od[2]=(bf16_t)d.z; od[3]=(bf16_t)d.w;
        *(bf16x4*)(Wub + i) = oa;
        *(bf16x4*)(Wvb + i) = ob;
        *(bf16x4*)(Wob + i) = od;
    }
}

// Toeplitz A-tiles: 128x32 (BK=32), diag offset (q-3)*32, 64 tiles x 8 heads.
__global__ __launch_bounds__(256) void build_toep_tiles(
    const float* __restrict__ zero, const float* __restrict__ pos,
    bf16_t* __restrict__ Atiles)
{
    const int q = blockIdx.x;        // 0..63
    const int h = blockIdx.y;        // 0..7
    const int doff = (q - 3) * 32;
    const int tid = threadIdx.x;
    bf16_t* dst = Atiles + ((size_t)h * 64 + q) * (128 * 32);
    const int e0 = tid * 16;
    const int r = e0 >> 5;
    const int cbase = e0 & 31;
    bf16_t vals[16];
    #pragma unroll
    for (int j = 0; j < 16; ++j) {
        const int d = doff + r - (cbase + j);
        float v = 0.f;
        if (d == 0) v = zero[h];
        else if (d > 0) v = pos[(size_t)h * (LQ - 1) + d - 1];
        vals[j] = (bf16_t)v;
    }
    *(bf16x8*)(dst + e0)     = *(bf16x8*)(vals);
    *(bf16x8*)(dst + e0 + 8) = *(bf16x8*)(vals + 8);
}

__global__ __launch_bounds__(256) void rmsnorm_kernel(
    const float* __restrict__ x, bf16_t* __restrict__ xn)
{
    const int row = blockIdx.x;           // 0..8191
    const int tid = threadIdx.x;
    const float4 v = ((const float4*)(x + (size_t)row * EQ))[tid];
    float ss = v.x*v.x + v.y*v.y + v.z*v.z + v.w*v.w;
    #pragma unroll
    for (int m = 32; m >= 1; m >>= 1) ss += __shfl_xor(ss, m, 64);
    __shared__ float red[4];
    const int wid = tid >> 6, lane = tid & 63;
    if (lane == 0) red[wid] = ss;
    __syncthreads();
    const float tot = red[0] + red[1] + red[2] + red[3];
    const float inv = 1.f / (sqrtf(tot * (1.f / EQ)) + 1e-8f);
    bf16x4 o;
    o[0] = (bf16_t)(v.x * inv); o[1] = (bf16_t)(v.y * inv);
    o[2] = (bf16_t)(v.z * inv); o[3] = (bf16_t)(v.w * inv);
    *(bf16x4*)(xn + (size_t)row * EQ + tid * 4) = o;
}

// ================================================================ pipeline family
// Best-measured structure (R13): 512 threads = 8 waves, BK=32, triple-buffered
// LDS 3 x 24 KB = 72 KB -> 2 blocks/CU; prefetch distance 2; 3 loads/thread/
// stage; boundary vmcnt(3), never 0 until tail; one barrier/tile; setprio;
// conflict-light swizzle (16B slot ^= (row>>1)&3, both sides); XCD chunking.

// ---------------------------------------------------------------- merged U+V GEMM
// BM=256, BN=128; waves 4M x 2N, wave tile 64x64, acc[4][4].  (verbatim R13)
// B = [Wu; Wv]: bx<16 -> U (silu, row-major); bx>=16 -> V (silu, (h,b,hd,t)
// via pair-wave LDS transpose, full 64-B t-runs).
__global__ __launch_bounds__(512, 2) void gemm_uv(
    const bf16_t* __restrict__ A, const bf16_t* __restrict__ Bm,
    const float* __restrict__ bbu, const float* __restrict__ bbv,
    bf16_t* __restrict__ Ub, bf16_t* __restrict__ Vt)
{
    constexpr int K = EQ;            // 1024
    constexpr int BUF = 24576;       // A 16K + B 8K
    __shared__ alignas(16) char smem[3 * BUF];   // 72 KB

    const int nwg   = gridDim.x * gridDim.y;
    const int bid0  = blockIdx.y * gridDim.x + blockIdx.x;
    const int chunkw = nwg >> 3;
    const int sb    = (bid0 & 7) * chunkw + (bid0 >> 3);
    const int bx    = sb % gridDim.x;
    const int by    = sb / gridDim.x;

    const int tid  = threadIdx.x;
    const int wid  = tid >> 6;          // 0..7
    const int lane = tid & 63;
    const int frow = lane & 15;
    const int c    = lane >> 4;
    const int m0 = by * 256;
    const int n0 = bx * 128;
    const int wm = wid >> 1, wn = wid & 1;
    const int wrm = wm * 64, wrn = wn * 64;

    const int g = (frow >> 1) & 3;
    const int offA0 = (wrm + frow) * 64 + ((c ^ g) << 4);
    const int offB0 = 16384 + (wrn + frow) * 64 + ((c ^ g) << 4);

    const int rA   = tid >> 2;          // 0..127
    const int soff = (((tid & 3) ^ ((rA >> 1) & 3)) << 4);
    const size_t lda2 = (size_t)K * 2;
    const char* sA = (const char*)A  + (size_t)(m0 + rA) * lda2 + soff;
    const char* sB = (const char*)Bm + (size_t)(n0 + rA) * lda2 + soff;

    auto STAGE = [&](int bf, int kt) {   // 3 loads / thread
        char* dA = smem + bf * BUF + wid * 1024;
        __builtin_amdgcn_global_load_lds(GAS1(sA + (size_t)kt * 64), LAS3(dA), 16, 0, 0);
        __builtin_amdgcn_global_load_lds(GAS1(sA + 128 * lda2 + (size_t)kt * 64),
                                         LAS3(dA + 8192), 16, 0, 0);
        char* dB = smem + bf * BUF + 16384 + wid * 1024;
        __builtin_amdgcn_global_load_lds(GAS1(sB + (size_t)kt * 64), LAS3(dB), 16, 0, 0);
    };

    f32x4 acc[4][4];
    #pragma unroll
    for (int i = 0; i < 4; ++i)
        #pragma unroll
        for (int j = 0; j < 4; ++j) acc[i][j] = (f32x4){0.f, 0.f, 0.f, 0.f};

    const int NT = K >> 5;              // 32

    STAGE(0, 0); STAGE(1, 1);
    asm volatile("s_waitcnt vmcnt(3)" ::: "memory");
    __builtin_amdgcn_s_barrier();

    int cur = 0, pb = 2;
    for (int t = 0; t < NT; ++t) {
        if (t + 2 < NT) STAGE(pb, t + 2);
        const char* base = smem + cur * BUF;
        bf16x8 av[4], bv[4];
        #pragma unroll
        for (int i = 0; i < 4; ++i) {
            av[i] = *(const bf16x8*)(base + offA0 + i * 1024);
            bv[i] = *(const bf16x8*)(base + offB0 + i * 1024);
        }
        __builtin_amdgcn_s_setprio(1);
        #pragma unroll
        for (int mi = 0; mi < 4; ++mi)
            #pragma unroll
            for (int ni = 0; ni < 4; ++ni)
                acc[mi][ni] = __builtin_amdgcn_mfma_f32_16x16x32_bf16(
                    av[mi], bv[ni], acc[mi][ni], 0, 0, 0);
        __builtin_amdgcn_s_setprio(0);
        if (t + 1 < NT) {
            if (t + 2 < NT) asm volatile("s_waitcnt vmcnt(3)" ::: "memory");
            else            asm volatile("s_waitcnt vmcnt(0)" ::: "memory");
            __builtin_amdgcn_s_barrier();
        }
        cur = (cur == 2) ? 0 : cur + 1;
        pb  = (pb  == 2) ? 0 : pb  + 1;
    }

    if (bx < 16) {
        const int fq = c * 4;
        #pragma unroll
        for (int mi = 0; mi < 4; ++mi) {
            #pragma unroll
            for (int ni = 0; ni < 4; ++ni) {
                const int gn = n0 + wrn + ni * 16 + frow;
                #pragma unroll
                for (int j = 0; j < 4; ++j) {
                    const int gm = m0 + wrm + mi * 16 + fq + j;
                    float v = acc[mi][ni][j] + bbu[gn];
                    v = v / (1.f + __expf(-v));
                    Ub[(size_t)gm * D1Q + gn] = (bf16_t)v;
                }
            }
        }
        return;
    }

    {   // V epilogue (verbatim R11/R13, passing)
        const int n0v = n0 - 2048;
        const int hh  = n0v >> 8;
        const int hdb = (n0v & 255) + wrn;
        float bb[4];
        #pragma unroll
        for (int ni = 0; ni < 4; ++ni) bb[ni] = bbv[n0v + wrn + ni * 16 + frow];

        bf16_t* chunk = (bf16_t*)smem + wn * 8448;
        #pragma unroll
        for (int p = 0; p < 2; ++p) {
            __syncthreads();
            #pragma unroll
            for (int mi = 0; mi < 4; ++mi) {
                #pragma unroll
                for (int nio = 0; nio < 2; ++nio) {
                    const int ni = p * 2 + nio;
                    const int nl = nio * 16 + frow;
                    const int tl = wm * 16 + mi * 4 + c;
                    #pragma unroll
                    for (int j = 0; j < 4; ++j) {
                        float v = acc[mi][ni][j] + bb[ni];
                        v = v / (1.f + __expf(-v));
                        chunk[nl * 264 + j * 64 + tl] = (bf16_t)v;
                    }
                }
            }
            __syncthreads();
            const int nl    = lane & 31;
            const int thalf = lane >> 5;
            const int b2    = wm;
            const int hd    = hdb + p * 32 + nl;
            const int t0    = (m0 >> 2) + thalf * 32;
            const bf16_t* src = chunk + nl * 264 + b2 * 64 + thalf * 32;
            bf16_t* dst = Vt + (((size_t)hh * 4 + b2) * 256 + hd) * (size_t)LQ + t0;
            #pragma unroll
            for (int u = 0; u < 4; ++u)
                *(bf16x8*)(dst + u * 8) = *(const bf16x8*)(src + u * 8);
        }
    }
}

// ---------------------------------------------------------------- Toeplitz GEMM
// Same pipeline family.  BM=128 (t), BN=256 (n=b*256+hd per head), BK=32;
// waves 2M x 4N (wrm=(wid>>2)*64, wrn=(wid&3)*64), wave tile 64x64.
// LDS: A 8K + B 16K = 24K x 3 = 72 KB -> 2 blocks/CU.
// Heavy-first 512 blocks; causal NT = 4*m_blk+4.
__global__ __launch_bounds__(512, 2) void gemm_toep(
    const bf16_t* __restrict__ VT, const bf16_t* __restrict__ Atiles,
    const bf16_t* __restrict__ U, bf16_t* __restrict__ O)
{
    constexpr int BUF = 24576;       // A 8K + B 16K
    __shared__ alignas(16) char smem[3 * BUF];   // 72 KB

    const int bid   = blockIdx.x;          // 0..511
    const int m_blk = 15 - (bid >> 5);     // heavy-first
    const int sub   = bid & 31;
    const int h     = sub >> 2;
    const int n0    = (sub & 3) * 256;
    const int m0    = m_blk * 128;

    const int tid  = threadIdx.x;
    const int wid  = tid >> 6;
    const int lane = tid & 63;
    const int frow = lane & 15;
    const int c    = lane >> 4;
    const int wrm  = (wid >> 2) * 64;
    const int wrn  = (wid & 3) * 64;

    const int g = (frow >> 1) & 3;
    const int offA0 = (wrm + frow) * 64 + ((c ^ g) << 4);
    const int offB0 = 8192 + (wrn + frow) * 64 + ((c ^ g) << 4);

    const int rA   = tid >> 2;          // 0..127
    const int soff = (((tid & 3) ^ ((rA >> 1) & 3)) << 4);
    const char* Ah = (const char*)Atiles + (size_t)h * 64 * 8192;
    const size_t ldb = (size_t)LQ * 2;
    const char* sB = (const char*)VT + ((size_t)h * 1024 + n0 + rA) * ldb + soff;

    auto STAGE = [&](int bf, int kt) {   // 3 loads / thread
        const int q = 4 * m_blk + 3 - kt;
        const char* s = Ah + (size_t)q * 8192 + (size_t)rA * 64 + soff;
        __builtin_amdgcn_global_load_lds(GAS1(s),
                                         LAS3(smem + bf * BUF + wid * 1024), 16, 0, 0);
        char* dB = smem + bf * BUF + 8192 + wid * 1024;
        __builtin_amdgcn_global_load_lds(GAS1(sB + (size_t)kt * 64), LAS3(dB), 16, 0, 0);
        __builtin_amdgcn_global_load_lds(GAS1(sB + 128 * ldb + (size_t)kt * 64),
                                         LAS3(dB + 8192), 16, 0, 0);
    };

    f32x4 acc[4][4];
    #pragma unroll
    for (int i = 0; i < 4; ++i)
        #pragma unroll
        for (int j = 0; j < 4; ++j) acc[i][j] = (f32x4){0.f, 0.f, 0.f, 0.f};

    const int NT = 4 * m_blk + 4;          // causal K-tiles, >= 4

    STAGE(0, 0); STAGE(1, 1);
    asm volatile("s_waitcnt vmcnt(3)" ::: "memory");
    __builtin_amdgcn_s_barrier();

    int cur = 0, pb = 2;
    for (int t = 0; t < NT; ++t) {
        if (t + 2 < NT) STAGE(pb, t + 2);
        const char* base = smem + cur * BUF;
        bf16x8 av[4], bv[4];
        #pragma unroll
        for (int i = 0; i < 4; ++i) {
            av[i] = *(const bf16x8*)(base + offA0 + i * 1024);
            bv[i] = *(const bf16x8*)(base + offB0 + i * 1024);
        }
        __builtin_amdgcn_s_setprio(1);
        #pragma unroll
        for (int mi = 0; mi < 4; ++mi)
            #pragma unroll
            for (int ni = 0; ni < 4; ++ni)
                acc[mi][ni] = __builtin_amdgcn_mfma_f32_16x16x32_bf16(
                    av[mi], bv[ni], acc[mi][ni], 0, 0, 0);
        __builtin_amdgcn_s_setprio(0);
        if (t + 1 < NT) {
            if (t + 2 < NT) asm volatile("s_waitcnt vmcnt(3)" ::: "memory");
            else            asm volatile("s_waitcnt vmcnt(0)" ::: "memory");
            __builtin_amdgcn_s_barrier();
        }
        cur = (cur == 2) ? 0 : cur + 1;
        pb  = (pb  == 2) ? 0 : pb  + 1;
    }

    // epilogue: gate with U, scatter to (t*4+b, h*256+hd)
    const int fq = c * 4;
    #pragma unroll
    for (int mi = 0; mi < 4; ++mi) {
        #pragma unroll
        for (int ni = 0; ni < 4; ++ni) {
            const int nn = n0 + wrn + ni * 16 + frow;   // 0..1023
            const int b  = nn >> 8, hd = nn & 255;
            #pragma unroll
            for (int j = 0; j < 4; ++j) {
                const int t = m0 + wrm + mi * 16 + fq + j;
                const size_t idx = ((size_t)t * BQ + b) * D1Q + h * HDQ + hd;
                const float uval = (float)U[idx];
                O[idx] = (bf16_t)(uval * acc[mi][ni][j]);
            }
        }
    }
}

// ---------------------------------------------------------------- final GEMM
// Same pipeline family, uv geometry verbatim (BM=256, BN=128, waves 4Mx2N).
// K=2048, NT=64.  Epilogue: acc + bias + residual -> f32 row-major.
__global__ __launch_bounds__(512, 2) void gemm_fin(
    const bf16_t* __restrict__ A, const bf16_t* __restrict__ Bm,
    const float* __restrict__ bias, const float* __restrict__ res,
    float* __restrict__ Cf)
{
    constexpr int K = D1Q, N = EQ;
    constexpr int BUF = 24576;       // A 16K + B 8K
    __shared__ alignas(16) char smem[3 * BUF];   // 72 KB

    const int nwg   = gridDim.x * gridDim.y;
    const int bid0  = blockIdx.y * gridDim.x + blockIdx.x;
    const int chunkw = nwg >> 3;
    const int sb    = (bid0 & 7) * chunkw + (bid0 >> 3);
    const int bx    = sb % gridDim.x;
    const int by    = sb / gridDim.x;

    const int tid  = threadIdx.x;
    const int wid  = tid >> 6;
    const int lane = tid & 63;
    const int frow = lane & 15;
    const int c    = lane >> 4;
    const int m0 = by * 256;
    const int n0 = bx * 128;
    const int wm = wid >> 1, wn = wid & 1;
    const int wrm = wm * 64, wrn = wn * 64;

    const int g = (frow >> 1) & 3;
    const int offA0 = (wrm + frow) * 64 + ((c ^ g) << 4);
    const int offB0 = 16384 + (wrn + frow) * 64 + ((c ^ g) << 4);

    const int rA   = tid >> 2;          // 0..127
    const int soff = (((tid & 3) ^ ((rA >> 1) & 3)) << 4);
    const size_t lda2 = (size_t)K * 2;
    const char* sA = (const char*)A  + (size_t)(m0 + rA) * lda2 + soff;
    const char* sB = (const char*)Bm + (size_t)(n0 + rA) * lda2 + soff;

    auto STAGE = [&](int bf, int kt) {   // 3 loads / thread
        char* dA = smem + bf * BUF + wid * 1024;
        __builtin_amdgcn_global_load_lds(GAS1(sA + (size_t)kt * 64), LAS3(dA), 16, 0, 0);
        __builtin_amdgcn_global_load_lds(GAS1(sA + 128 * lda2 + (size_t)kt * 64),
                                         LAS3(dA + 8192), 16, 0, 0);
        char* dB = smem + bf * BUF + 16384 + wid * 1024;
        __builtin_amdgcn_global_load_lds(GAS1(sB + (size_t)kt * 64), LAS3(dB), 16, 0, 0);
    };

    f32x4 acc[4][4];
    #pragma unroll
    for (int i = 0; i < 4; ++i)
        #pragma unroll
        for (int j = 0; j < 4; ++j) acc[i][j] = (f32x4){0.f, 0.f, 0.f, 0.f};

    const int NT = K >> 5;              // 64

    STAGE(0, 0); STAGE(1, 1);
    asm volatile("s_waitcnt vmcnt(3)" ::: "memory");
    __builtin_amdgcn_s_barrier();

    int cur = 0, pb = 2;
    for (int t = 0; t < NT; ++t) {
        if (t + 2 < NT) STAGE(pb, t + 2);
        const char* base = smem + cur * BUF;
        bf16x8 av[4], bv[4];
        #pragma unroll
        for (int i = 0; i < 4; ++i) {
            av[i] = *(const bf16x8*)(base + offA0 + i * 1024);
            bv[i] = *(const bf16x8*)(base + offB0 + i * 1024);
        }
        __builtin_amdgcn_s_setprio(1);
        #pragma unroll
        for (int mi = 0; mi < 4; ++mi)
            #pragma unroll
            for (int ni = 0; ni < 4; ++ni)
                acc[mi][ni] = __builtin_amdgcn_mfma_f32_16x16x32_bf16(
                    av[mi], bv[ni], acc[mi][ni], 0, 0, 0);
        __builtin_amdgcn_s_setprio(0);
        if (t + 1 < NT) {
            if (t + 2 < NT) asm volatile("s_waitcnt vmcnt(3)" ::: "memory");
            else            asm volatile("s_waitcnt vmcnt(0)" ::: "memory");
            __builtin_amdgcn_s_barrier();
        }
        cur = (cur == 2) ? 0 : cur + 1;
        pb  = (pb  == 2) ? 0 : pb  + 1;
    }

    const int fq = c * 4;
    #pragma unroll
    for (int mi = 0; mi < 4; ++mi) {
        #pragma unroll
        for (int ni = 0; ni < 4; ++ni) {
            const int gn = n0 + wrn + ni * 16 + frow;
            #pragma unroll
            for (int j = 0; j < 4; ++j) {
                const int gm = m0 + wrm + mi * 16 + fq + j;
                Cf[(size_t)gm * N + gn] =
                    acc[mi][ni][j] + bias[gn] + res[(size_t)gm * N + gn];
            }
        }
    }
}

// ---------------------------------------------------------------- launch

extern "C" void kernel_launch(void* const* d_in, const int* in_sizes, int n_in,
                              void* d_out, int out_size, void* d_ws, size_t ws_size,
                              hipStream_t stream)
{
    const float* x    = (const float*)d_in[0];
    const float* Wu   = (const float*)d_in[1];
    const float* bu   = (const float*)d_in[2];
    const float* Wv   = (const float*)d_in[3];
    const float* bv   = (const float*)d_in[4];
    const float* Wo   = (const float*)d_in[5];
    const float* bo   = (const float*)d_in[6];
    const float* zero = (const float*)d_in[7];
    const float* pos  = (const float*)d_in[8];
    float* out = (float*)d_out;

    char* ws = (char*)d_ws;
    size_t off = 0;
    auto alloc = [&](size_t bytes) {
        char* p = ws + off;
        off += (bytes + 255) & ~(size_t)255;
        return p;
    };
    bf16_t* xn     = (bf16_t*)alloc((size_t)NBQ * EQ * 2);
    bf16_t* Wub    = (bf16_t*)alloc((size_t)D1Q * EQ * 2);    // | contiguous:
    bf16_t* Wvb    = (bf16_t*)alloc((size_t)D1Q * EQ * 2);    // | B = [Wu; Wv]
    bf16_t* Wob    = (bf16_t*)alloc((size_t)EQ * D1Q * 2);
    bf16_t* Atiles = (bf16_t*)alloc((size_t)HQ * 64 * 4096 * 2);  // 4 MB
    bf16_t* Ub     = (bf16_t*)alloc((size_t)NBQ * D1Q * 2);
    bf16_t* VTb    = (bf16_t*)alloc((size_t)NBQ * D1Q * 2);   // (h,b,hd,t)
    bf16_t* Ob     = (bf16_t*)alloc((size_t)NBQ * D1Q * 2);

    convert_kernel<<<2048, 256, 0, stream>>>(Wu, Wv, Wo, Wub, Wvb, Wob);
    build_toep_tiles<<<dim3(64, 8), 256, 0, stream>>>(zero, pos, Atiles);
    rmsnorm_kernel<<<NBQ, 256, 0, stream>>>(x, xn);

    // merged U+V: M=8192, N=4096, K=1024 — 256x128 tiles, 1024 blocks, 2/CU
    dim3 g1(32, NBQ / 256);          // (32, 32) = 1024 blocks
    gemm_uv<<<g1, 512, 0, stream>>>(xn, Wub, bu, bv, Ub, VTb);

    // toep: per-head causal, 128x256 tiles, heavy-first 512 blocks, 2/CU
    gemm_toep<<<512, 512, 0, stream>>>(VTb, Atiles, Ub, Ob);

    // final: M=8192, N=1024, K=2048 — 256x128 tiles, 256 blocks, 2/CU
    dim3 g2(EQ / 128, NBQ / 256);    // (8, 32)
    gemm_fin<<<g2, 512, 0, stream>>>(Ob, Wob, bo, x, out);
}